// Round 13
// baseline (166.163 us; speedup 1.0000x reference)
//
#include <hip/hip_runtime.h>

#define N_NODES 50000
#define DIM 256
#define NEG 0.2f
#define LN_EPS 1e-5f
#define SCAT_BLOCKS 2048
#define NTILES 782            // ceil(50000/64) chunks of 64 nodes
#define GRID_F 256            // 1 block/CU (128 KB LDS)

typedef __attribute__((ext_vector_type(8))) short short8;   // 8 x bf16 (4 VGPRs)
typedef __attribute__((ext_vector_type(4))) float f32x4;    // MFMA accumulator

__device__ __forceinline__ unsigned short f2bf(float x) {   // RNE fp32 -> bf16
    unsigned int u = __builtin_bit_cast(unsigned int, x);
    u += 0x7fffu + ((u >> 16) & 1u);
    return (unsigned short)(u >> 16);
}

__device__ __forceinline__ void load_lds16(const void* g, void* l) {
    // async global->LDS, 16B/lane, dest = wave-uniform base + lane*16 (linear)
    __builtin_amdgcn_global_load_lds((const unsigned int*)g, (unsigned int*)l, 16, 0, 0);
}

__device__ __forceinline__ short8 cvt_bfrag(float4 a4, float4 b4) {
    short8 r;
    r[0] = (short)f2bf(a4.x); r[1] = (short)f2bf(a4.y);
    r[2] = (short)f2bf(a4.z); r[3] = (short)f2bf(a4.w);
    r[4] = (short)f2bf(b4.x); r[5] = (short)f2bf(b4.y);
    r[6] = (short)f2bf(b4.z); r[7] = (short)f2bf(b4.w);
    return r;
}

// ---------- prep: Wr -> fragment-ordered bf16 WrF  +  relation byte-mask scatter ----------
// WrF layout (proven r2-r12): frag f = kk*16+mt (kk = 32-wide k-step, mt = 16-col m-tile),
// 64 lanes x 16B: WrF[(f*64+lane)*8 + j] = bf16(Wr[kk*32 + (lane>>4)*8 + j][mt*16 + (lane&15)])
__global__ __launch_bounds__(256) void prep(
    const float* __restrict__ Wr, unsigned short* __restrict__ WrF,
    const int* __restrict__ d0, const int* __restrict__ d1, const int* __restrict__ d2,
    int E, unsigned char* __restrict__ mask)
{
    if (blockIdx.x < 32) {                       // 32*256 = 8192 = 128 frags x 64 lanes
        const int o    = blockIdx.x * 256 + threadIdx.x;
        const int lane = o & 63;
        const int frag = o >> 6;                 // kk*16 + mt
        const int mt = frag & 15, kk = frag >> 4;
        const int ln = lane & 15, quad = lane >> 4;
        const float* src = Wr + (size_t)(kk * 32 + quad * 8) * DIM + mt * 16 + ln;
        short8 v;
        #pragma unroll
        for (int j = 0; j < 8; ++j) v[j] = (short)f2bf(src[(size_t)j * DIM]);
        *(short8*)(WrF + (size_t)o * 8) = v;
    } else {
        // racing byte-stores of the same value are benign; memset zeroed the mask
        const int total = 3 * E;
        for (int i = (blockIdx.x - 32) * 256 + (int)threadIdx.x; i < total;
             i += SCAT_BLOCKS * 256) {
            const int* d; int base, e;
            if (i >= 2 * E)  { d = d2; e = i - 2 * E; base = 2 * N_NODES; }
            else if (i >= E) { d = d1; e = i - E;     base = N_NODES; }
            else             { d = d0; e = i;         base = 0; }
            mask[base + d[e]] = (unsigned char)1;
        }
    }
}

// ---------- fused GEMM: W resident per block, split-M waves, minimal barriers ----------
// r12's decisive result: occupancy 13->28% changed nothing -> not occupancy-bound.
// Every variant re-staged 128 KB of W per block behind vmcnt-draining barriers and
// bunched HBM into short bursts (duty ~25% = the measured 1.7/6.3 TB/s). This
// kernel stages W ONCE per block (128 KB LDS resident, 512 threads, 1 block/CU,
// grid 256) and strides over ~3 chunks of 64 nodes. Waves use r12's proven
// split-M (acc 32, wave owns heads 2h..2h+1 -> live ~105 regs, far under any cap;
// avoids r6/r7's allocator trap). Steady state per chunk: feat reads + mask +
// stores (independent streams from 8 desynchronized waves), 64 MFMA from resident
// W, ONE barrier (only for the 2-float LayerNorm exchange, double-buffered).
// Zero W re-staging, zero W-drains. qp/kp/wgt/acc bit-identical to r12 (passed).
__global__ __launch_bounds__(512, 1) void fused_mfma(
    const float* __restrict__ feat, const unsigned short* __restrict__ WrF,
    const float* __restrict__ br, const float* __restrict__ rel_q,
    const float* __restrict__ rel_k, const float* __restrict__ gamma,
    const float* __restrict__ beta_p, const unsigned char* __restrict__ mask,
    float* __restrict__ out)
{
    __shared__ char lds[133120];                 // [0,128K) W frags; [128K,+2K) ss xchg x2
    const int lane = threadIdx.x & 63;
    const int wave = threadIdx.x >> 6;           // 0..7
    const int mhalf = wave & 1;                  // head pair: mt 8*mhalf .. 8*mhalf+7
    const int ng = wave >> 1;                    // node group 0..3 (16 nodes each)
    const int ln = lane & 15;      // node within group / MFMA n
    const int quad = lane >> 4;    // MFMA k-quad & D-row-quad

    // ---- stage full WrF once: wave w stages frags [16w, 16w+16) ----
    {
        const char* g = (const char*)WrF;
        #pragma unroll
        for (int r = 0; r < 16; ++r) {
            const int off = (wave * 16 + r) * 1024;      // wave-uniform LDS base
            load_lds16(g + off + lane * 16, lds + off);
        }
    }
    __syncthreads();                             // W resident (only vmcnt-heavy drain)

    int cbuf = 0;
    for (int t = blockIdx.x; t < NTILES; t += GRID_F) {  // uniform trip per block
        int node = t * 64 + ng * 16 + ln;
        const bool valid = node < N_NODES;
        if (!valid) node = N_NODES - 1;          // clamp: loads safe, store guarded

        // mask bytes (epilogue-only; issue first)
        const int m0 = (int)mask[node];
        const int m1 = (int)mask[N_NODES + node];
        const int m2 = (int)mask[2 * N_NODES + node];

        // feat row -> bf16 B-fragments, 4 chunks of 2 ksteps (peak F = 16 regs)
        const float* fptr = feat + (size_t)node * DIM + quad * 8;
        short8 bfr[8];
        #pragma unroll
        for (int c = 0; c < 4; ++c) {
            float4 F0[2], F1[2];
            #pragma unroll
            for (int k = 0; k < 2; ++k) {
                F0[k] = *(const float4*)(fptr + (c * 2 + k) * 32);
                F1[k] = *(const float4*)(fptr + (c * 2 + k) * 32 + 4);
            }
            #pragma unroll
            for (int k = 0; k < 2; ++k) bfr[c * 2 + k] = cvt_bfrag(F0[k], F1[k]);
        }

        f32x4 acc[8];
        #pragma unroll
        for (int j = 0; j < 8; ++j) acc[j] = (f32x4){0.f, 0.f, 0.f, 0.f};

        #pragma unroll
        for (int kk = 0; kk < 8; ++kk) {         // W from resident LDS, no waits
            const char* wb = lds + (kk * 16 + mhalf * 8) * 1024 + lane * 16;
            #pragma unroll
            for (int j = 0; j < 8; ++j) {        // static j: acc never runtime-indexed
                const short8 a = *(const short8*)(wb + j * 1024);
                acc[j] = __builtin_amdgcn_mfma_f32_16x16x32_bf16(a, bfr[kk], acc[j], 0, 0, 0);
            }
        }

        // ---- epilogue (r12-proven): bias + per-head dots over own 8 m-tiles ----
        float qp[2] = {0.f, 0.f}, kp[2] = {0.f, 0.f};
        #pragma unroll
        for (int j = 0; j < 8; ++j) {
            const int cbase = (mhalf * 8 + j) * 16 + quad * 4;
            const float4 bb = *(const float4*)(br + cbase);
            acc[j][0] += bb.x; acc[j][1] += bb.y; acc[j][2] += bb.z; acc[j][3] += bb.w;
            const float4 rq = *(const float4*)(rel_q + cbase);
            const float4 rk = *(const float4*)(rel_k + cbase);
            const int hh = j >> 2;
            qp[hh] += acc[j][0] * rq.x + acc[j][1] * rq.y + acc[j][2] * rq.z + acc[j][3] * rq.w;
            kp[hh] += acc[j][0] * rk.x + acc[j][1] * rk.y + acc[j][2] * rk.z + acc[j][3] * rk.w;
        }
        #pragma unroll
        for (int hh = 0; hh < 2; ++hh) {
            qp[hh] += __shfl_xor(qp[hh], 16); qp[hh] += __shfl_xor(qp[hh], 32);
            kp[hh] += __shfl_xor(kp[hh], 16); kp[hh] += __shfl_xor(kp[hh], 32);
        }

        const int cnt = m0 + m1 + m2;

        float wgt[2];
        #pragma unroll
        for (int hh = 0; hh < 2; ++hh) {
            const float q = qp[hh];
            const float qk = q + kp[hh];
            const float a = q  > 0.f ? q  : NEG * q;    // inactive-relation logit
            const float b = qk > 0.f ? qk : NEG * qk;   // active/self logit
            const float mx = fmaxf(a, b);
            const float eb = (float)(cnt + 1) * __expf(b - mx);
            const float ea = (float)(3 - cnt) * __expf(a - mx);
            wgt[hh] = eb / (eb + ea);
        }

        float sum = 0.f, ssq = 0.f;              // partial over own half-row
        #pragma unroll
        for (int j = 0; j < 8; ++j) {
            const float w = wgt[j >> 2];
            #pragma unroll
            for (int r = 0; r < 4; ++r) {
                float v = fmaxf(acc[j][r] * w, 0.f);    // ReLU
                acc[j][r] = v;
                sum += v; ssq += v * v;
            }
        }
        sum += __shfl_xor(sum, 16); sum += __shfl_xor(sum, 32);
        ssq += __shfl_xor(ssq, 16); ssq += __shfl_xor(ssq, 32);

        // ---- cross-wave sum/ssq exchange: double-buffered region, ONE barrier ----
        float* ss = (float*)(lds + 131072 + cbuf * 1024);
        if (quad == 0) {
            const int idx = ((ng * 2 + mhalf) * 16 + ln) * 2;
            ss[idx] = sum; ss[idx + 1] = ssq;
        }
        __syncthreads();                         // the only steady-state barrier
        {
            const int pidx = ((ng * 2 + (1 - mhalf)) * 16 + ln) * 2;
            sum += ss[pidx]; ssq += ss[pidx + 1];
        }
        cbuf ^= 1;                               // next chunk writes the other region

        const float mu = sum * (1.f / 256.f);
        const float var = ssq * (1.f / 256.f) - mu * mu;
        const float rstd = rsqrtf(var + LN_EPS);

        if (valid) {
            float* optr = out + (size_t)node * DIM;
            #pragma unroll
            for (int j = 0; j < 8; ++j) {
                const int cbase = (mhalf * 8 + j) * 16 + quad * 4;
                const float4 g = *(const float4*)(gamma + cbase);
                const float4 b = *(const float4*)(beta_p + cbase);
                float4 r;
                r.x = (acc[j][0] - mu) * rstd * g.x + b.x;
                r.y = (acc[j][1] - mu) * rstd * g.y + b.y;
                r.z = (acc[j][2] - mu) * rstd * g.z + b.z;
                r.w = (acc[j][3] - mu) * rstd * g.w + b.w;
                *(float4*)(optr + cbase) = r;
            }
        }
    }
}

extern "C" void kernel_launch(void* const* d_in, const int* in_sizes, int n_in,
                              void* d_out, int out_size, void* d_ws, size_t ws_size,
                              hipStream_t stream) {
    const float* feat  = (const float*)d_in[0];
    // d_in[1] Wl, d_in[2] bl, d_in[5] attn_l, d_in[6] attn_r, edge_src_*: dead code
    const float* Wr    = (const float*)d_in[3];
    const float* br    = (const float*)d_in[4];
    const float* rel_q = (const float*)d_in[7];
    const float* rel_k = (const float*)d_in[8];
    const float* gamma = (const float*)d_in[9];
    const float* beta  = (const float*)d_in[10];
    const int* dst0 = (const int*)d_in[12];
    const int* dst1 = (const int*)d_in[14];
    const int* dst2 = (const int*)d_in[16];
    const int E = in_sizes[12];

    // d_ws layout: WrF fragment-ordered bf16 (131072 B) | byte mask (150016 B)
    unsigned short* WrF = (unsigned short*)d_ws;
    unsigned char* mask = (unsigned char*)d_ws + DIM * DIM * 2;

    hipMemsetAsync(mask, 0, 150016, stream);
    prep<<<32 + SCAT_BLOCKS, 256, 0, stream>>>(Wr, WrF, dst0, dst1, dst2, E, mask);
    fused_mfma<<<GRID_F, 512, 0, stream>>>(
        feat, WrF, br, rel_q, rel_k, gamma, beta, mask, (float*)d_out);
}

// Round 14
// 153.608 us; speedup vs baseline: 1.0817x; 1.0817x over previous
//
#include <hip/hip_runtime.h>

#define N_NODES 50000
#define DIM 256
#define NEG 0.2f
#define LN_EPS 1e-5f
#define SCAT_BLOCKS 512

typedef __attribute__((ext_vector_type(8))) short short8;   // 8 x bf16 (4 VGPRs)
typedef __attribute__((ext_vector_type(4))) float f32x4;    // MFMA accumulator

__device__ __forceinline__ unsigned short f2bf(float x) {   // RNE fp32 -> bf16
    unsigned int u = __builtin_bit_cast(unsigned int, x);
    u += 0x7fffu + ((u >> 16) & 1u);
    return (unsigned short)(u >> 16);
}

__device__ __forceinline__ void load_lds16(const void* g, void* l) {
    // async global->LDS, 16B/lane, dest = wave-uniform base + lane*16 (linear)
    __builtin_amdgcn_global_load_lds((const unsigned int*)g, (unsigned int*)l, 16, 0, 0);
}

__device__ __forceinline__ short8 cvt_bfrag(float4 a4, float4 b4) {
    short8 r;
    r[0] = (short)f2bf(a4.x); r[1] = (short)f2bf(a4.y);
    r[2] = (short)f2bf(a4.z); r[3] = (short)f2bf(a4.w);
    r[4] = (short)f2bf(b4.x); r[5] = (short)f2bf(b4.y);
    r[6] = (short)f2bf(b4.z); r[7] = (short)f2bf(b4.w);
    return r;
}

// ---------- prep: Wr -> fragment-ordered bf16 WrF  +  relation byte-mask scatter ----------
// WrF layout (proven r2-r13): frag f = kk*16+mt (kk = 32-wide k-step, mt = 16-col m-tile),
// 64 lanes x 16B: WrF[(f*64+lane)*8 + j] = bf16(Wr[kk*32 + (lane>>4)*8 + j][mt*16 + (lane&15)])
__global__ __launch_bounds__(256) void prep(
    const float* __restrict__ Wr, unsigned short* __restrict__ WrF,
    const int* __restrict__ d0, const int* __restrict__ d1, const int* __restrict__ d2,
    int E, unsigned char* __restrict__ mask)
{
    if (blockIdx.x < 32) {                       // 32*256 = 8192 = 128 frags x 64 lanes
        const int o    = blockIdx.x * 256 + threadIdx.x;
        const int lane = o & 63;
        const int frag = o >> 6;                 // kk*16 + mt
        const int mt = frag & 15, kk = frag >> 4;
        const int ln = lane & 15, quad = lane >> 4;
        const float* src = Wr + (size_t)(kk * 32 + quad * 8) * DIM + mt * 16 + ln;
        short8 v;
        #pragma unroll
        for (int j = 0; j < 8; ++j) v[j] = (short)f2bf(src[(size_t)j * DIM]);
        *(short8*)(WrF + (size_t)o * 8) = v;
    } else {
        // racing byte-stores of the same value are benign; memset zeroed the mask
        const int total = 3 * E;
        for (int i = (blockIdx.x - 32) * 256 + (int)threadIdx.x; i < total;
             i += SCAT_BLOCKS * 256) {
            const int* d; int base, e;
            if (i >= 2 * E)  { d = d2; e = i - 2 * E; base = 2 * N_NODES; }
            else if (i >= E) { d = d1; e = i - E;     base = N_NODES; }
            else             { d = d0; e = i;         base = 0; }
            mask[base + d[e]] = (unsigned char)1;
        }
    }
}

// ---------- fused MFMA GEMM + analytic-collapse epilogue (r9 verbatim: measured best) ----------
// Block = 4 waves x 16 nodes, 2 blocks/CU (2 x 80 KB LDS). Schedule:
//   stage ksteps 0-4 (80 KB) + feat prefetch + bfr convert -> sync -> MFMA k0-3
//   -> sync -> restage k5-7 (48 KB) || MFMA k4 (resident B region) -> sync
//   -> MFMA k5-7 -> epilogue -> LDS-transpose coalesced C-store.
// 13 rounds of structural variants (finer pipelining, persistent W, zero-LDS,
// split-M 4 blocks/CU, W-resident minimal-barrier) all landed 42-47+ us or
// spilled; this structure's 41.5 us is the measured floor. Fused counters to
// expect: VGPR 124, LDS 81920, FETCH ~26 MB, WRITE ~50 MB, no bank conflicts.
__global__ __launch_bounds__(256, 2) void fused_mfma(
    const float* __restrict__ feat, const unsigned short* __restrict__ WrF,
    const float* __restrict__ br, const float* __restrict__ rel_q,
    const float* __restrict__ rel_k, const float* __restrict__ gamma,
    const float* __restrict__ beta_p, const unsigned char* __restrict__ mask,
    float* __restrict__ out)
{
    __shared__ unsigned short lds[40960];        // 80 KB: A=[0,64K) ping, B=[64K,80K) kstep4
    const int lane = threadIdx.x & 63;
    const int wave = threadIdx.x >> 6;
    const int ln = lane & 15;      // node within wave / MFMA n
    const int quad = lane >> 4;    // MFMA k-quad & D-row-quad
    int node = blockIdx.x * 64 + wave * 16 + ln;
    const bool valid = node < N_NODES;
    if (!valid) node = N_NODES - 1;              // clamp: loads safe, store guarded

    // ---- stage ksteps 0-3 into A (16 x 1KB per wave) + kstep 4 into B (4 x 1KB) ----
    {
        const char* g = (const char*)WrF;
        #pragma unroll
        for (int r = 0; r < 16; ++r) {
            const int off = wave * 16384 + r * 1024;     // wave-uniform LDS base
            load_lds16(g + off + lane * 16, (char*)lds + off);
        }
        #pragma unroll
        for (int r = 0; r < 4; ++r) {
            const int off = wave * 4096 + r * 1024;      // within kstep-4 block
            load_lds16(g + 65536 + off + lane * 16, (char*)lds + 65536 + off);
        }
    }

    // mask bytes (epilogue-only; hide latency now)
    const int m0 = (int)mask[node];
    const int m1 = (int)mask[N_NODES + node];
    const int m2 = (int)mask[2 * N_NODES + node];

    // full feat-row prefetch + one-time bf16 conversion
    const float* fptr = feat + (size_t)node * DIM + quad * 8;
    float4 F0[8], F1[8];
    #pragma unroll
    for (int kk = 0; kk < 8; ++kk) {
        F0[kk] = *(const float4*)(fptr + kk * 32);
        F1[kk] = *(const float4*)(fptr + kk * 32 + 4);
    }
    short8 bfr[8];
    #pragma unroll
    for (int kk = 0; kk < 8; ++kk) bfr[kk] = cvt_bfrag(F0[kk], F1[kk]);

    f32x4 acc[16];
    #pragma unroll
    for (int mt = 0; mt < 16; ++mt) acc[mt] = (f32x4){0.f, 0.f, 0.f, 0.f};

    __syncthreads();                             // vmcnt drain: ksteps 0-4 staged

    #pragma unroll
    for (int kk = 0; kk < 4; ++kk) {
        #pragma unroll
        for (int mt = 0; mt < 16; ++mt) {
            const short8 a = *(const short8*)((const char*)lds
                               + (kk * 16 + mt) * 1024 + lane * 16);
            acc[mt] = __builtin_amdgcn_mfma_f32_16x16x32_bf16(a, bfr[kk], acc[mt], 0, 0, 0);
        }
    }

    __syncthreads();                             // all waves done reading A (ksteps 0-3)

    // issue restage of ksteps 5-7 into A (48 chunks: 12 x 1KB per wave) ...
    {
        const char* g = (const char*)WrF + 81920;        // kstep-5 source base
        #pragma unroll
        for (int r = 0; r < 12; ++r) {
            const int off = (wave * 12 + r) * 1024;
            load_lds16(g + off + lane * 16, (char*)lds + off);
        }
    }
    // ... and compute kstep 4 from resident B while those loads are in flight
    #pragma unroll
    for (int mt = 0; mt < 16; ++mt) {
        const short8 a = *(const short8*)((const char*)lds
                           + 65536 + mt * 1024 + lane * 16);
        acc[mt] = __builtin_amdgcn_mfma_f32_16x16x32_bf16(a, bfr[4], acc[mt], 0, 0, 0);
    }

    __syncthreads();                             // vmcnt drain: ksteps 5-7 staged

    #pragma unroll
    for (int kk = 5; kk < 8; ++kk) {
        #pragma unroll
        for (int mt = 0; mt < 16; ++mt) {
            const short8 a = *(const short8*)((const char*)lds
                               + ((kk - 5) * 16 + mt) * 1024 + lane * 16);
            acc[mt] = __builtin_amdgcn_mfma_f32_16x16x32_bf16(a, bfr[kk], acc[mt], 0, 0, 0);
        }
    }

    // ---- epilogue: bias, per-head dots, softmax weight, ReLU, LayerNorm ----
    float qp[4] = {0.f, 0.f, 0.f, 0.f}, kp[4] = {0.f, 0.f, 0.f, 0.f};
    #pragma unroll
    for (int mt = 0; mt < 16; ++mt) {
        const int cbase = mt * 16 + quad * 4;
        const float4 bb = *(const float4*)(br + cbase);
        acc[mt][0] += bb.x; acc[mt][1] += bb.y; acc[mt][2] += bb.z; acc[mt][3] += bb.w;
        const float4 rq = *(const float4*)(rel_q + cbase);
        const float4 rk = *(const float4*)(rel_k + cbase);
        const int h = mt >> 2;
        qp[h] += acc[mt][0] * rq.x + acc[mt][1] * rq.y + acc[mt][2] * rq.z + acc[mt][3] * rq.w;
        kp[h] += acc[mt][0] * rk.x + acc[mt][1] * rk.y + acc[mt][2] * rk.z + acc[mt][3] * rk.w;
    }
    #pragma unroll
    for (int h = 0; h < 4; ++h) {
        qp[h] += __shfl_xor(qp[h], 16); qp[h] += __shfl_xor(qp[h], 32);
        kp[h] += __shfl_xor(kp[h], 16); kp[h] += __shfl_xor(kp[h], 32);
    }

    const int cnt = m0 + m1 + m2;

    float wgt[4];
    #pragma unroll
    for (int h = 0; h < 4; ++h) {
        const float q = qp[h];
        const float qk = q + kp[h];
        const float a = q  > 0.f ? q  : NEG * q;    // inactive-relation logit
        const float b = qk > 0.f ? qk : NEG * qk;   // active/self logit
        const float mx = fmaxf(a, b);
        const float eb = (float)(cnt + 1) * __expf(b - mx);
        const float ea = (float)(3 - cnt) * __expf(a - mx);
        wgt[h] = eb / (eb + ea);
    }

    float sum = 0.f, ssq = 0.f;
    #pragma unroll
    for (int mt = 0; mt < 16; ++mt) {
        const float w = wgt[mt >> 2];
        #pragma unroll
        for (int r = 0; r < 4; ++r) {
            float v = fmaxf(acc[mt][r] * w, 0.f);   // ReLU
            acc[mt][r] = v;
            sum += v; ssq += v * v;
        }
    }
    sum += __shfl_xor(sum, 16); sum += __shfl_xor(sum, 32);
    ssq += __shfl_xor(ssq, 16); ssq += __shfl_xor(ssq, 32);
    const float mu = sum * (1.f / 256.f);
    const float var = ssq * (1.f / 256.f) - mu * mu;
    const float rstd = rsqrtf(var + LN_EPS);

    #pragma unroll
    for (int mt = 0; mt < 16; ++mt) {
        const int cbase = mt * 16 + quad * 4;
        const float4 g = *(const float4*)(gamma + cbase);
        const float4 b = *(const float4*)(beta_p + cbase);
        acc[mt][0] = (acc[mt][0] - mu) * rstd * g.x + b.x;
        acc[mt][1] = (acc[mt][1] - mu) * rstd * g.y + b.y;
        acc[mt][2] = (acc[mt][2] - mu) * rstd * g.z + b.z;
        acc[mt][3] = (acc[mt][3] - mu) * rstd * g.w + b.w;
    }

    // ---- coalesced C-store via LDS transpose (wave-private 16 KB slice) ----
    __syncthreads();                             // all waves done reading W; LDS reusable
    {
        char* slice = (char*)lds + wave * 16384;
        #pragma unroll
        for (int mt = 0; mt < 16; ++mt) {        // node-major write, XOR-swizzled cols
            const int col = (mt * 64 + quad * 16) ^ ((ln & 7) << 4);
            *(f32x4*)(slice + ln * 1024 + col) = acc[mt];
        }
        asm volatile("s_waitcnt lgkmcnt(0)" ::: "memory");
        __builtin_amdgcn_sched_barrier(0);
        const int base_node = blockIdx.x * 64 + wave * 16;
        #pragma unroll
        for (int r = 0; r < 16; ++r) {           // dense row reads + coalesced stores
            if (base_node + r < N_NODES) {       // wave-uniform guard
                const int off = (lane * 16) ^ ((r & 7) << 4);
                const float4 v = *(const float4*)(slice + r * 1024 + off);
                *(float4*)(out + (size_t)(base_node + r) * DIM + lane * 4) = v;
            }
        }
    }
}

extern "C" void kernel_launch(void* const* d_in, const int* in_sizes, int n_in,
                              void* d_out, int out_size, void* d_ws, size_t ws_size,
                              hipStream_t stream) {
    const float* feat  = (const float*)d_in[0];
    // d_in[1] Wl, d_in[2] bl, d_in[5] attn_l, d_in[6] attn_r, edge_src_*: dead code
    const float* Wr    = (const float*)d_in[3];
    const float* br    = (const float*)d_in[4];
    const float* rel_q = (const float*)d_in[7];
    const float* rel_k = (const float*)d_in[8];
    const float* gamma = (const float*)d_in[9];
    const float* beta  = (const float*)d_in[10];
    const int* dst0 = (const int*)d_in[12];
    const int* dst1 = (const int*)d_in[14];
    const int* dst2 = (const int*)d_in[16];
    const int E = in_sizes[12];

    // d_ws layout: WrF fragment-ordered bf16 (131072 B) | byte mask (150016 B)
    unsigned short* WrF = (unsigned short*)d_ws;
    unsigned char* mask = (unsigned char*)d_ws + DIM * DIM * 2;

    hipMemsetAsync(mask, 0, 150016, stream);
    prep<<<32 + SCAT_BLOCKS, 256, 0, stream>>>(Wr, WrF, dst0, dst1, dst2, E, mask);
    fused_mfma<<<(N_NODES + 63) / 64, 256, 0, stream>>>(
        feat, WrF, br, rel_q, rel_k, gamma, beta, mask, (float*)d_out);
}